// Round 2
// baseline (2873.425 us; speedup 1.0000x reference)
//
#include <hip/hip_runtime.h>
#include <hip/hip_bf16.h>
#include <hip/hip_fp16.h>

// QuantizedLinear: out[M,N] = x[M,K] . W^T[N,K] + bias, W = (q - zero)*scale per group
// M=8192 (B*S), K=4096 (IN), N=11008 (OUT), 32 groups of 128 along K.
// Round 2: same as round 1 but scales/zeros read as fp32 (harness promotes
// jnp.float16 inputs to float32 — the {bf16,f32,int32} type universe).
// Round-1 failure (absmax 3.3e7) is only consistent with fp16 reads aliasing
// an fp32 buffer (random mantissa half-words -> +/-65504-scale junk).

typedef __bf16 bf16x8 __attribute__((ext_vector_type(8)));
typedef __bf16 bf16x4 __attribute__((ext_vector_type(4)));
typedef float  floatx4 __attribute__((ext_vector_type(4)));

constexpr int Mdim = 8192;
constexpr int Kdim = 4096;
constexpr int Ndim = 11008;
constexpr int NG   = 32;    // groups per output row

#define BM 128
#define BN 128
#define BK 32

__device__ __forceinline__ __bf16 f2b(float f) { return (__bf16)f; }  // fptrunc = RNE

__global__ __launch_bounds__(256, 2)
void qlinear_mfma(const float* __restrict__ x,
                  const int*   __restrict__ qw,
                  const float* __restrict__ scales,
                  const float* __restrict__ zeros,
                  const float* __restrict__ bias,
                  float* __restrict__ out)
{
    __shared__ __align__(16) __bf16 sA[BM * BK];
    __shared__ __align__(16) __bf16 sB[BN * BK];

    const int n0 = blockIdx.x * BN;
    const int m0 = blockIdx.y * BM;

    const int t    = threadIdx.x;
    const int lane = t & 63;
    const int wave = t >> 6;
    const int wr   = (wave >> 1) * 64;   // wave row origin in tile
    const int wc   = (wave & 1) * 64;    // wave col origin in tile
    const int quad = lane >> 4;
    const int l16  = lane & 15;

    // staging coords: 256 threads cover 32 rows x 8 float4-columns per pass
    const int sr = t >> 3;          // 0..31 (row within pass)
    const int sc = (t & 7) * 4;     // 0..28 step 4 (k within tile)

    floatx4 acc[4][4] = {};

    for (int k0 = 0; k0 < Kdim; k0 += BK) {
        const int g = k0 >> 7;   // BK=32 divides group_size=128: one group per tile

        // ---- stage A: x fp32 -> bf16 LDS (4 passes of 32 rows) ----
        #pragma unroll
        for (int p = 0; p < 4; ++p) {
            const int row = p * 32 + sr;
            const float4 v = *(const float4*)(x + (m0 + row) * Kdim + k0 + sc);
            bf16x4 w;
            w[0] = f2b(v.x); w[1] = f2b(v.y); w[2] = f2b(v.z); w[3] = f2b(v.w);
            *(bf16x4*)(&sA[row * BK + sc]) = w;
        }
        // ---- stage B: dequant qweight -> bf16 LDS ----
        #pragma unroll
        for (int p = 0; p < 4; ++p) {
            const int row = p * 32 + sr;       // n within tile
            const int n   = n0 + row;
            const int4 q  = *(const int4*)(qw + n * Kdim + k0 + sc);
            const float sf = scales[n * NG + g];
            const float zf = zeros [n * NG + g];
            bf16x4 w;
            w[0] = f2b(((float)q.x - zf) * sf);
            w[1] = f2b(((float)q.y - zf) * sf);
            w[2] = f2b(((float)q.z - zf) * sf);
            w[3] = f2b(((float)q.w - zf) * sf);
            *(bf16x4*)(&sB[row * BK + sc]) = w;
        }
        __syncthreads();

        // ---- fragments + MFMA: each wave 4x4 of 16x16x32 ----
        bf16x8 af[4], bfr[4];
        #pragma unroll
        for (int i = 0; i < 4; ++i)
            af[i] = *(bf16x8*)(&sA[(wr + i * 16 + l16) * BK + quad * 8]);
        #pragma unroll
        for (int j = 0; j < 4; ++j)
            bfr[j] = *(bf16x8*)(&sB[(wc + j * 16 + l16) * BK + quad * 8]);

        #pragma unroll
        for (int i = 0; i < 4; ++i)
            #pragma unroll
            for (int j = 0; j < 4; ++j)
                acc[i][j] = __builtin_amdgcn_mfma_f32_16x16x32_bf16(
                                af[i], bfr[j], acc[i][j], 0, 0, 0);

        __syncthreads();
    }

    // ---- epilogue: C/D layout row=quad*4+r, col=l16; add bias, store fp32 ----
    float bj[4];
    #pragma unroll
    for (int j = 0; j < 4; ++j) bj[j] = bias[n0 + wc + j * 16 + l16];

    #pragma unroll
    for (int i = 0; i < 4; ++i) {
        const int m = m0 + wr + i * 16 + quad * 4;
        #pragma unroll
        for (int j = 0; j < 4; ++j) {
            const int n = n0 + wc + j * 16 + l16;
            float* o = out + (size_t)m * Ndim + n;
            #pragma unroll
            for (int r = 0; r < 4; ++r)
                o[(size_t)r * Ndim] = acc[i][j][r] + bj[j];
        }
    }
}

extern "C" void kernel_launch(void* const* d_in, const int* in_sizes, int n_in,
                              void* d_out, int out_size, void* d_ws, size_t ws_size,
                              hipStream_t stream) {
    const float* x      = (const float*)d_in[0];
    const int*   qwt    = (const int*)d_in[1];
    const float* scales = (const float*)d_in[2];
    const float* zeros  = (const float*)d_in[3];
    const float* bias   = (const float*)d_in[4];
    float* out = (float*)d_out;

    dim3 grid(Ndim / BN, Mdim / BM);   // 86 x 64 = 5504 blocks
    qlinear_mfma<<<grid, 256, 0, stream>>>(x, qwt, scales, zeros, bias, out);
}